// Round 4
// baseline (673.138 us; speedup 1.0000x reference)
//
#include <hip/hip_runtime.h>

#define G 128
#define N 32
#define H 128
#define L 6

typedef _Float16 half8 __attribute__((ext_vector_type(8)));
typedef float f32x4 __attribute__((ext_vector_type(4)));

// ---------------------------------------------------------------------------
// W pre-pack: Wpk[l] = { hi[h][k], lo[h][k] } f16 images of Wc[l][k][h]^T.
// Fragment-ready layout: conv_mlp A-fragment = one b128 load. grid = 6.
// ---------------------------------------------------------------------------
__global__ __launch_bounds__(256) void k_packW(
    const float* __restrict__ Wc, _Float16* __restrict__ Wpk) {
  int l = blockIdx.x, tid = threadIdx.x;
  const float* W = Wc + (size_t)l * 16384;
  _Float16* hi = Wpk + (size_t)l * 32768;
  _Float16* lo = hi + 16384;
  for (int idx = tid; idx < 16384; idx += 256) {
    int k = idx >> 7, h = idx & 127;
    float v = W[idx];                       // W[k][h]
    _Float16 a = (_Float16)v;
    hi[h * 128 + k] = a;
    lo[h * 128 + k] = (_Float16)(v - (float)a);
  }
}

// ---------------------------------------------------------------------------
// E1: P0 = emb_x @ W0 + b0, P1 = emb_x @ W1 + b1. grid=2.
// ---------------------------------------------------------------------------
__global__ __launch_bounds__(256) void k_emb_mm(
    const float* __restrict__ emb_x,
    const float* __restrict__ W0, const float* __restrict__ b0, float* __restrict__ P0,
    const float* __restrict__ W1, const float* __restrict__ b1, float* __restrict__ P1) {
  const float* W = blockIdx.x ? W1 : W0;
  const float* b = blockIdx.x ? b1 : b0;
  float*       P = blockIdx.x ? P1 : P0;
  __shared__ float embs_t[128 * 32];   // [k][i]
  int tid = threadIdx.x;
  {
    int i = tid & 31, k0 = (tid >> 5) * 16;
    const float* src = emb_x + i * 128 + k0;
#pragma unroll
    for (int m = 0; m < 16; m++) embs_t[(k0 + m) * 32 + i] = src[m];
  }
  __syncthreads();
  int i  = tid >> 3;
  int h0 = (tid & 7) * 16;
  float acc[16];
#pragma unroll
  for (int hh = 0; hh < 16; hh++) acc[hh] = b[h0 + hh];
  for (int k = 0; k < 128; k++) {
    float a = embs_t[k * 32 + i];
    const float4* wr = (const float4*)(W + k * 128 + h0);
    float4 w0 = wr[0], w1 = wr[1], w2 = wr[2], w3 = wr[3];
    acc[0]  += a * w0.x; acc[1]  += a * w0.y; acc[2]  += a * w0.z; acc[3]  += a * w0.w;
    acc[4]  += a * w1.x; acc[5]  += a * w1.y; acc[6]  += a * w1.z; acc[7]  += a * w1.w;
    acc[8]  += a * w2.x; acc[9]  += a * w2.y; acc[10] += a * w2.z; acc[11] += a * w2.w;
    acc[12] += a * w3.x; acc[13] += a * w3.y; acc[14] += a * w3.z; acc[15] += a * w3.w;
  }
  float4* dst = (float4*)(P + i * 128 + h0);
  dst[0] = make_float4(acc[0], acc[1], acc[2], acc[3]);
  dst[1] = make_float4(acc[4], acc[5], acc[6], acc[7]);
  dst[2] = make_float4(acc[8], acc[9], acc[10], acc[11]);
  dst[3] = make_float4(acc[12], acc[13], acc[14], acc[15]);
}

// ---------------------------------------------------------------------------
// E2: build X h-planar: Xp[g][h][i*32+j]. One WG per graph.
// ---------------------------------------------------------------------------
__global__ __launch_bounds__(256) void k_buildX(
    const int* __restrict__ x_idx, const int* __restrict__ tf_idx,
    const float* __restrict__ P0, const float* __restrict__ P1,
    const float* __restrict__ emb_tf, float* __restrict__ Xp) {
  int g = blockIdx.x, tid = threadIdx.x;
  __shared__ float x0t[128 * 32];
  __shared__ float x1t[128 * 32];
  __shared__ float etf[128 * 16];
  __shared__ int   tfs[1024];
  {
    int i = tid & 31, h0 = (tid >> 5) * 16;
    int r = x_idx[g * 32 + i];
    const float* s0 = P0 + r * 128 + h0;
    const float* s1 = P1 + r * 128 + h0;
#pragma unroll
    for (int m = 0; m < 16; m++) {
      x0t[(h0 + m) * 32 + i] = s0[m];
      x1t[(h0 + m) * 32 + i] = s1[m];
    }
  }
  {
    int t = tid & 15, h0 = (tid >> 4) * 8;
    const float* s = emb_tf + t * 128 + h0;
#pragma unroll
    for (int m = 0; m < 8; m++) etf[(h0 + m) * 16 + t] = s[m];
  }
  ((int4*)tfs)[tid] = ((const int4*)(tf_idx + (size_t)g * 1024))[tid];
  __syncthreads();
  int i = tid >> 3, j0 = (tid & 7) * 4;
  int t0 = tfs[i * 32 + j0 + 0], t1 = tfs[i * 32 + j0 + 1];
  int t2 = tfs[i * 32 + j0 + 2], t3 = tfs[i * 32 + j0 + 3];
  float* outg = Xp + ((size_t)g << 17);
  for (int h = 0; h < 128; h++) {
    float a = x0t[h * 32 + i];
    const float* x1r = x1t + h * 32;
    const float* er  = etf + h * 16;
    float4 v;
    v.x = a * x1r[j0 + 0] * er[t0];
    v.y = a * x1r[j0 + 1] * er[t1];
    v.z = a * x1r[j0 + 2] * er[t2];
    v.w = a * x1r[j0 + 3] * er[t3];
    *(float4*)(outg + h * 1024 + tid * 4) = v;
  }
}

// ---------------------------------------------------------------------------
// K1 v5 (MFMA, zero-LDS, zero-barrier): tXp = relu(LN(X @ Wc[l] + bc[l])).
// A-fragments: direct b128 loads from pre-packed W^T hi/lo images (L2-hot).
// B-fragments: 8 strided global dwords (k-major in h-planar X) + in-reg
// f16 hi/lo split. 3 MFMA per tile (dropped lo*lo ~2^-22 rel). LN in
// registers via shfl_xor(16/32). grid = G*4, 2 waves/SIMD.
// ---------------------------------------------------------------------------
__global__ __launch_bounds__(256, 2) void k_conv_mlp(
    const float* __restrict__ Xp, const _Float16* __restrict__ Wpk,
    const float* __restrict__ bcl, const float* __restrict__ gcl,
    const float* __restrict__ ccl, float* __restrict__ tXp) {
  int g = blockIdx.x >> 2, qb = blockIdx.x & 3;
  int tid = threadIdx.x;
  int lane = tid & 63, wv = tid >> 6;
  int x = lane & 15, quad = lane >> 4;

  f32x4 acc[4][8];
#pragma unroll
  for (int hh = 0; hh < 8; hh++) {
    float4 b4 = *(const float4*)(bcl + hh * 16 + quad * 4);
    f32x4 bi; bi[0] = b4.x; bi[1] = b4.y; bi[2] = b4.z; bi[3] = b4.w;
#pragma unroll
    for (int pt = 0; pt < 4; pt++) acc[pt][hh] = bi;
  }

  const float* Xg = Xp + ((size_t)g << 17) + qb * 256 + wv * 64 + x;
  const _Float16* Wlo = Wpk + 16384;

#pragma unroll
  for (int c = 0; c < 4; c++) {
    int kb = c * 32 + quad * 8;
    half8 bh[4], bl[4];
#pragma unroll
    for (int pt = 0; pt < 4; pt++) {
      const float* xc = Xg + pt * 16 + (size_t)kb * 1024;
#pragma unroll
      for (int i = 0; i < 8; i++) {
        float v = xc[(size_t)i * 1024];
        _Float16 hi = (_Float16)v;
        bh[pt][i] = hi;
        bl[pt][i] = (_Float16)(v - (float)hi);
      }
    }
#pragma unroll
    for (int hh = 0; hh < 8; hh++) {
      int wo = (hh * 16 + x) * 128 + kb;
      half8 ah = *(const half8*)(Wpk + wo);
      half8 al = *(const half8*)(Wlo + wo);
#pragma unroll
      for (int pt = 0; pt < 4; pt++) {
        acc[pt][hh] = __builtin_amdgcn_mfma_f32_16x16x32_f16(ah, bh[pt], acc[pt][hh], 0, 0, 0);
        acc[pt][hh] = __builtin_amdgcn_mfma_f32_16x16x32_f16(ah, bl[pt], acc[pt][hh], 0, 0, 0);
        acc[pt][hh] = __builtin_amdgcn_mfma_f32_16x16x32_f16(al, bh[pt], acc[pt][hh], 0, 0, 0);
      }
    }
  }

  // ---- LN over h (two-pass, in registers + quad butterflies) ----
  float gm[4], gr[4];
#pragma unroll
  for (int pt = 0; pt < 4; pt++) {
    float s = 0.f;
#pragma unroll
    for (int hh = 0; hh < 8; hh++)
#pragma unroll
      for (int r = 0; r < 4; r++) s += acc[pt][hh][r];
    s += __shfl_xor(s, 16);
    s += __shfl_xor(s, 32);
    float m = s * (1.f / 128.f);
    float qv = 0.f;
#pragma unroll
    for (int hh = 0; hh < 8; hh++)
#pragma unroll
      for (int r = 0; r < 4; r++) { float d = acc[pt][hh][r] - m; qv += d * d; }
    qv += __shfl_xor(qv, 16);
    qv += __shfl_xor(qv, 32);
    gm[pt] = m;
    gr[pt] = rsqrtf(qv * (1.f / 128.f) + 1e-5f);
  }
  // ---- normalize + relu + store ----
  int pbase = qb * 256 + wv * 64;
#pragma unroll
  for (int hh = 0; hh < 8; hh++) {
    float4 g4 = *(const float4*)(gcl + hh * 16 + quad * 4);
    float4 c4 = *(const float4*)(ccl + hh * 16 + quad * 4);
    float ga[4] = {g4.x, g4.y, g4.z, g4.w};
    float ca[4] = {c4.x, c4.y, c4.z, c4.w};
#pragma unroll
    for (int r = 0; r < 4; r++) {
      int h = hh * 16 + quad * 4 + r;
      float* dst = tXp + (((size_t)(g * 128 + h)) << 10) + pbase + x;
#pragma unroll
      for (int pt = 0; pt < 4; pt++) {
        float v = (acc[pt][hh][r] - gm[pt]) * gr[pt] * ga[r] + ca[r];
        dst[pt * 16] = fmaxf(v, 0.f);
      }
    }
  }
}

// ---------------------------------------------------------------------------
// K2: X[g,h,i,j] += sum_k tX * A. 8 h-planes per WG (grid G*16), 2 per wave.
// LAST=true (layer 5): instead of writing X back, reduce mean over j and
// emit xs[g*32+i][h] directly (saves 64MB write + 64MB tail re-read).
// ---------------------------------------------------------------------------
template <bool LAST>
__global__ __launch_bounds__(256, 4) void k_conv_msg(
    const float* __restrict__ tXp, const int* __restrict__ ea_idx,
    const int* __restrict__ adj, const float* __restrict__ emb_ea,
    float* __restrict__ Xp, float* __restrict__ xs) {
  int g  = blockIdx.x >> 4;
  int hb = (blockIdx.x & 15) * 8;
  int tid = threadIdx.x, wv = tid >> 6, lane = tid & 63;
  __shared__ unsigned char c8[1024];
  __shared__ float eacs[8][20];
  __shared__ __align__(16) float tXs[4][32 * 36];
  __shared__ __align__(16) float As[4][32 * 36];
  {
    int4 ev = ((const int4*)(ea_idx + (size_t)g * 1024))[tid];
    int4 av = ((const int4*)(adj   + (size_t)g * 1024))[tid];
    uchar4 c;
    c.x = av.x ? (unsigned char)ev.x : (unsigned char)16;
    c.y = av.y ? (unsigned char)ev.y : (unsigned char)16;
    c.z = av.z ? (unsigned char)ev.z : (unsigned char)16;
    c.w = av.w ? (unsigned char)ev.w : (unsigned char)16;
    ((uchar4*)c8)[tid] = c;
  }
  if (tid < 128) {
    int hh = tid >> 4, e = tid & 15;
    eacs[hh][e] = emb_ea[e * 128 + hb + hh];
  }
  if (tid >= 128 && tid < 136) eacs[tid - 128][16] = 0.f;
  __syncthreads();
  int i0 = (lane >> 3) * 4, j0 = (lane & 7) * 4;
  float* tw = tXs[wv];
  float* aw = As[wv];
#pragma unroll 1
  for (int pl = 0; pl < 2; pl++) {
    int hh = wv * 2 + pl;
    int h  = hb + hh;
    const float4* tp = (const float4*)(tXp + (((size_t)(g * 128 + h)) << 10));
#pragma unroll
    for (int m = 0; m < 4; m++) {
      int f = lane + 64 * m;
      float4 v = tp[f];
      *(float4*)&tw[(f >> 3) * 36 + (f & 7) * 4] = v;
    }
#pragma unroll
    for (int m = 0; m < 4; m++) {
      int qd = lane + 64 * m;
      uchar4 cc = ((const uchar4*)c8)[qd];
      float4 a;
      a.x = eacs[hh][cc.x]; a.y = eacs[hh][cc.y];
      a.z = eacs[hh][cc.z]; a.w = eacs[hh][cc.w];
      *(float4*)&aw[(qd >> 3) * 36 + (qd & 7) * 4] = a;
    }
    float4 a0 = {0, 0, 0, 0}, a1 = a0, a2 = a0, a3 = a0;
#pragma unroll
    for (int kb = 0; kb < 8; kb++) {
      int k4 = kb * 4;
      float4 t0 = *(const float4*)&tw[(i0 + 0) * 36 + k4];
      float4 t1 = *(const float4*)&tw[(i0 + 1) * 36 + k4];
      float4 t2 = *(const float4*)&tw[(i0 + 2) * 36 + k4];
      float4 t3 = *(const float4*)&tw[(i0 + 3) * 36 + k4];
      float4 b0 = *(const float4*)&aw[(k4 + 0) * 36 + j0];
      float4 b1 = *(const float4*)&aw[(k4 + 1) * 36 + j0];
      float4 b2 = *(const float4*)&aw[(k4 + 2) * 36 + j0];
      float4 b3 = *(const float4*)&aw[(k4 + 3) * 36 + j0];
      a0.x += t0.x * b0.x; a0.y += t0.x * b0.y; a0.z += t0.x * b0.z; a0.w += t0.x * b0.w;
      a0.x += t0.y * b1.x; a0.y += t0.y * b1.y; a0.z += t0.y * b1.z; a0.w += t0.y * b1.w;
      a0.x += t0.z * b2.x; a0.y += t0.z * b2.y; a0.z += t0.z * b2.z; a0.w += t0.z * b2.w;
      a0.x += t0.w * b3.x; a0.y += t0.w * b3.y; a0.z += t0.w * b3.z; a0.w += t0.w * b3.w;
      a1.x += t1.x * b0.x; a1.y += t1.x * b0.y; a1.z += t1.x * b0.z; a1.w += t1.x * b0.w;
      a1.x += t1.y * b1.x; a1.y += t1.y * b1.y; a1.z += t1.y * b1.z; a1.w += t1.y * b1.w;
      a1.x += t1.z * b2.x; a1.y += t1.z * b2.y; a1.z += t1.z * b2.z; a1.w += t1.z * b2.w;
      a1.x += t1.w * b3.x; a1.y += t1.w * b3.y; a1.z += t1.w * b3.z; a1.w += t1.w * b3.w;
      a2.x += t2.x * b0.x; a2.y += t2.x * b0.y; a2.z += t2.x * b0.z; a2.w += t2.x * b0.w;
      a2.x += t2.y * b1.x; a2.y += t2.y * b1.y; a2.z += t2.y * b1.z; a2.w += t2.y * b1.w;
      a2.x += t2.z * b2.x; a2.y += t2.z * b2.y; a2.z += t2.z * b2.z; a2.w += t2.z * b2.w;
      a2.x += t2.w * b3.x; a2.y += t2.w * b3.y; a2.z += t2.w * b3.z; a2.w += t2.w * b3.w;
      a3.x += t3.x * b0.x; a3.y += t3.x * b0.y; a3.z += t3.x * b0.z; a3.w += t3.x * b0.w;
      a3.x += t3.y * b1.x; a3.y += t3.y * b1.y; a3.z += t3.y * b1.z; a3.w += t3.y * b1.w;
      a3.x += t3.z * b2.x; a3.y += t3.z * b2.y; a3.z += t3.z * b2.z; a3.w += t3.z * b2.w;
      a3.x += t3.w * b3.x; a3.y += t3.w * b3.y; a3.z += t3.w * b3.z; a3.w += t3.w * b3.w;
    }
    float* xr = Xp + (((size_t)(g * 128 + h)) << 10);
    float4* r0 = (float4*)&xr[(i0 + 0) * 32 + j0];
    float4* r1 = (float4*)&xr[(i0 + 1) * 32 + j0];
    float4* r2 = (float4*)&xr[(i0 + 2) * 32 + j0];
    float4* r3 = (float4*)&xr[(i0 + 3) * 32 + j0];
    float4 x0 = *r0, x1 = *r1, x2 = *r2, x3 = *r3;
    x0.x += a0.x; x0.y += a0.y; x0.z += a0.z; x0.w += a0.w;
    x1.x += a1.x; x1.y += a1.y; x1.z += a1.z; x1.w += a1.w;
    x2.x += a2.x; x2.y += a2.y; x2.z += a2.z; x2.w += a2.w;
    x3.x += a3.x; x3.y += a3.y; x3.z += a3.z; x3.w += a3.w;
    if (!LAST) {
      *r0 = x0; *r1 = x1; *r2 = x2; *r3 = x3;
    } else {
      // fused OpPoolingSubg2D mean over j: reduce across j-group lanes
      float s0 = (x0.x + x0.y) + (x0.z + x0.w);
      float s1 = (x1.x + x1.y) + (x1.z + x1.w);
      float s2 = (x2.x + x2.y) + (x2.z + x2.w);
      float s3 = (x3.x + x3.y) + (x3.z + x3.w);
      s0 += __shfl_xor(s0, 1); s0 += __shfl_xor(s0, 2); s0 += __shfl_xor(s0, 4);
      s1 += __shfl_xor(s1, 1); s1 += __shfl_xor(s1, 2); s1 += __shfl_xor(s1, 4);
      s2 += __shfl_xor(s2, 1); s2 += __shfl_xor(s2, 2); s2 += __shfl_xor(s2, 4);
      s3 += __shfl_xor(s3, 1); s3 += __shfl_xor(s3, 2); s3 += __shfl_xor(s3, 4);
      if ((lane & 7) == 0) {
        float* xo = xs + ((size_t)(g * 32 + i0)) * 128 + h;
        xo[0]   = s0 * (1.f / 32.f);
        xo[128] = s1 * (1.f / 32.f);
        xo[256] = s2 * (1.f / 32.f);
        xo[384] = s3 * (1.f / 32.f);
      }
    }
  }
}

// ---------------------------------------------------------------------------
// T2: xs -> @Wp+bp -> LN -> relu -> sum_i -> @Wq1+bq1 -> LN -> relu ->
//     @Wq2+bq2. One WG per graph; no serial tid==0 loops (wave butterflies).
// ---------------------------------------------------------------------------
__global__ __launch_bounds__(256) void k_tail2(
    const float* __restrict__ xs,
    const float* __restrict__ Wp, const float* __restrict__ bp,
    const float* __restrict__ gp, const float* __restrict__ cp,
    const float* __restrict__ Wq1, const float* __restrict__ bq1,
    const float* __restrict__ gq1, const float* __restrict__ cq1,
    const float* __restrict__ Wq2, const float* __restrict__ bq2,
    float* __restrict__ out) {
  int g = blockIdx.x, tid = threadIdx.x;
  __shared__ float xsl[32 * 132];
  __shared__ float y_s[32 * 132];
  __shared__ float red8[32][9];
  __shared__ float hg_s[128];
  __shared__ float q_s[128];
  __shared__ float stat[2];
  {
    const float4* src = (const float4*)(xs + (size_t)g * 4096);
#pragma unroll
    for (int m = 0; m < 4; m++) {
      int f = m * 256 + tid;
      int row = f >> 5, col = (f & 31) * 4;
      *(float4*)&xsl[row * 132 + col] = src[f];
    }
  }
  __syncthreads();
  int i_ = tid >> 3, ht = tid & 7, h0 = ht * 16;
  float acc[16];
#pragma unroll
  for (int hh = 0; hh < 16; hh++) acc[hh] = bp[h0 + hh];
  for (int k = 0; k < 128; k++) {
    float a = xsl[i_ * 132 + k];
    const float4* wr = (const float4*)(Wp + k * 128 + h0);
    float4 w0 = wr[0], w1 = wr[1], w2 = wr[2], w3 = wr[3];
    acc[0]  += a * w0.x; acc[1]  += a * w0.y; acc[2]  += a * w0.z; acc[3]  += a * w0.w;
    acc[4]  += a * w1.x; acc[5]  += a * w1.y; acc[6]  += a * w1.z; acc[7]  += a * w1.w;
    acc[8]  += a * w2.x; acc[9]  += a * w2.y; acc[10] += a * w2.z; acc[11] += a * w2.w;
    acc[12] += a * w3.x; acc[13] += a * w3.y; acc[14] += a * w3.z; acc[15] += a * w3.w;
  }
  // per-i LN (8 threads per i via LDS stats; wave-local rows, in-order DS)
  {
    float s = 0.f;
#pragma unroll
    for (int hh = 0; hh < 16; hh++) s += acc[hh];
    red8[i_][ht] = s;
  }
  __syncthreads();
  float m = 0.f;
#pragma unroll
  for (int t = 0; t < 8; t++) m += red8[i_][t];
  m *= (1.f / 128.f);
  __syncthreads();
  {
    float q = 0.f;
#pragma unroll
    for (int hh = 0; hh < 16; hh++) { float d = acc[hh] - m; q += d * d; }
    red8[i_][ht] = q;
  }
  __syncthreads();
  float v = 0.f;
#pragma unroll
  for (int t = 0; t < 8; t++) v += red8[i_][t];
  float r = rsqrtf(v * (1.f / 128.f) + 1e-5f);
#pragma unroll
  for (int hh = 0; hh < 16; hh++) {
    int hcol = h0 + hh;
    y_s[i_ * 132 + hcol] = fmaxf((acc[hh] - m) * r * gp[hcol] + cp[hcol], 0.f);
  }
  __syncthreads();
  if (tid < 128) {
    float sh = 0.f;
#pragma unroll
    for (int ii = 0; ii < 32; ii++) sh += y_s[ii * 132 + tid];
    hg_s[tid] = sh;
  }
  __syncthreads();
  if (tid < 128) {
    float a = bq1[tid];
    for (int k = 0; k < 128; k++) a += hg_s[k] * Wq1[k * 128 + tid];
    q_s[tid] = a;
  }
  __syncthreads();
  if (tid < 64) {
    float s2 = q_s[tid] + q_s[tid + 64];
    s2 += __shfl_xor(s2, 1);  s2 += __shfl_xor(s2, 2);  s2 += __shfl_xor(s2, 4);
    s2 += __shfl_xor(s2, 8);  s2 += __shfl_xor(s2, 16); s2 += __shfl_xor(s2, 32);
    if (tid == 0) stat[0] = s2 * (1.f / 128.f);
  }
  __syncthreads();
  float mq = stat[0];
  if (tid < 64) {
    float d0 = q_s[tid] - mq, d1 = q_s[tid + 64] - mq;
    float v2 = d0 * d0 + d1 * d1;
    v2 += __shfl_xor(v2, 1);  v2 += __shfl_xor(v2, 2);  v2 += __shfl_xor(v2, 4);
    v2 += __shfl_xor(v2, 8);  v2 += __shfl_xor(v2, 16); v2 += __shfl_xor(v2, 32);
    if (tid == 0) stat[1] = rsqrtf(v2 * (1.f / 128.f) + 1e-5f);
  }
  __syncthreads();
  float rq = stat[1];
  if (tid < 64) {
    float a0 = fmaxf((q_s[tid]      - mq) * rq * gq1[tid]      + cq1[tid],      0.f) * Wq2[tid];
    float a1 = fmaxf((q_s[tid + 64] - mq) * rq * gq1[tid + 64] + cq1[tid + 64], 0.f) * Wq2[tid + 64];
    float t = a0 + a1;
    t += __shfl_xor(t, 1);  t += __shfl_xor(t, 2);  t += __shfl_xor(t, 4);
    t += __shfl_xor(t, 8);  t += __shfl_xor(t, 16); t += __shfl_xor(t, 32);
    if (tid == 0) out[g] = t + bq2[0];
  }
}

// ---------------------------------------------------------------------------
extern "C" void kernel_launch(void* const* d_in, const int* in_sizes, int n_in,
                              void* d_out, int out_size, void* d_ws, size_t ws_size,
                              hipStream_t stream) {
  const int*   x_idx  = (const int*)d_in[0];
  const int*   ea_idx = (const int*)d_in[1];
  const int*   tf_idx = (const int*)d_in[2];
  const int*   adj    = (const int*)d_in[3];
  const float* emb_x  = (const float*)d_in[4];
  const float* emb_ea = (const float*)d_in[5];
  const float* emb_tf = (const float*)d_in[6];
  const float* W0  = (const float*)d_in[7];
  const float* b0  = (const float*)d_in[8];
  const float* W1  = (const float*)d_in[9];
  const float* b1  = (const float*)d_in[10];
  const float* Wc  = (const float*)d_in[11];
  const float* bc  = (const float*)d_in[12];
  const float* gc  = (const float*)d_in[13];
  const float* cc  = (const float*)d_in[14];
  const float* Wp  = (const float*)d_in[15];
  const float* bp  = (const float*)d_in[16];
  const float* gp  = (const float*)d_in[17];
  const float* cp  = (const float*)d_in[18];
  const float* Wq1 = (const float*)d_in[19];
  const float* bq1 = (const float*)d_in[20];
  const float* gq1 = (const float*)d_in[21];
  const float* cq1 = (const float*)d_in[22];
  const float* Wq2 = (const float*)d_in[23];
  const float* bq2 = (const float*)d_in[24];
  float* out = (float*)d_out;

  float* ws  = (float*)d_ws;
  float* Xp  = ws;                                   // 16,777,216 f
  float* tXp = ws + (size_t)16777216;                // 16,777,216 f
  float* P0  = ws + (size_t)33554432;                // 4096 f
  float* P1  = P0 + 4096;                            // 4096 f
  float* xs  = ws + (size_t)33562624;                // 524,288 f
  _Float16* Wpk = (_Float16*)(ws + (size_t)34086912); // 6*32768 f16

  k_packW<<<6, 256, 0, stream>>>(Wc, Wpk);
  k_emb_mm<<<2, 256, 0, stream>>>(emb_x, W0, b0, P0, W1, b1, P1);
  k_buildX<<<G, 256, 0, stream>>>(x_idx, tf_idx, P0, P1, emb_tf, Xp);
  for (int l = 0; l < L; l++) {
    k_conv_mlp<<<G * 4, 256, 0, stream>>>(Xp, Wpk + (size_t)l * 32768,
                                          bc + l * H, gc + l * H, cc + l * H, tXp);
    if (l < L - 1)
      k_conv_msg<false><<<G * 16, 256, 0, stream>>>(tXp, ea_idx, adj, emb_ea, Xp, xs);
    else
      k_conv_msg<true><<<G * 16, 256, 0, stream>>>(tXp, ea_idx, adj, emb_ea, Xp, xs);
  }
  k_tail2<<<G, 256, 0, stream>>>(xs, Wp, bp, gp, cp, Wq1, bq1, gq1, cq1, Wq2, bq2, out);
}